// Round 2
// baseline (28779.974 us; speedup 1.0000x reference)
//
#include <hip/hip_runtime.h>
#include <math.h>

#define B_  50
#define T_  512
#define I_  1024
#define H_  512
#define NG_ 2048
#define BP  64   // padded batch stride for transposed state buffers
#define NBLK 256 // persistent scan grid size (== CU count; all co-resident)

__device__ __forceinline__ float sigmf(float x) {
    return 1.0f / (1.0f + __expf(-x));
}
// overflow-safe tanh via e^{-2|x|} in (0,1]
__device__ __forceinline__ float tanh_fast(float x) {
    float ax = fabsf(x);
    float e  = __expf(-2.0f * ax);
    float t  = (1.0f - e) / (1.0f + e);
    return copysignf(t, x);
}

// ---------------------------------------------------------------------------
// C[m][n] = bias[n] + sum_k A[m][k] * W[n][k]
// 128x128 tile, K-step 16, 256 threads, 8x8 accum per thread.
// ---------------------------------------------------------------------------
__global__ __launch_bounds__(256) void gemm_bias(
    const float* __restrict__ A, const float* __restrict__ W,
    const float* __restrict__ bias, float* __restrict__ C,
    int M, int N, int K) {
    __shared__ float As[16][132];
    __shared__ float Ws[16][132];
    const int tid = threadIdx.x;
    const int m0 = blockIdx.y * 128, n0 = blockIdx.x * 128;
    const int lr = tid >> 2;            // 0..63 tile row
    const int lk = (tid & 3) << 2;      // 0,4,8,12 k offset
    const int tx = tid & 15, ty = tid >> 4;

    float acc[8][8];
#pragma unroll
    for (int i = 0; i < 8; ++i)
#pragma unroll
        for (int j = 0; j < 8; ++j) acc[i][j] = 0.0f;

    for (int k0 = 0; k0 < K; k0 += 16) {
        float4 a0 = *(const float4*)(A + (size_t)(m0 + lr) * K + k0 + lk);
        float4 a1 = *(const float4*)(A + (size_t)(m0 + lr + 64) * K + k0 + lk);
        float4 w0 = *(const float4*)(W + (size_t)(n0 + lr) * K + k0 + lk);
        float4 w1 = *(const float4*)(W + (size_t)(n0 + lr + 64) * K + k0 + lk);
        __syncthreads();
        As[lk + 0][lr] = a0.x; As[lk + 1][lr] = a0.y; As[lk + 2][lr] = a0.z; As[lk + 3][lr] = a0.w;
        As[lk + 0][lr + 64] = a1.x; As[lk + 1][lr + 64] = a1.y; As[lk + 2][lr + 64] = a1.z; As[lk + 3][lr + 64] = a1.w;
        Ws[lk + 0][lr] = w0.x; Ws[lk + 1][lr] = w0.y; Ws[lk + 2][lr] = w0.z; Ws[lk + 3][lr] = w0.w;
        Ws[lk + 0][lr + 64] = w1.x; Ws[lk + 1][lr + 64] = w1.y; Ws[lk + 2][lr + 64] = w1.z; Ws[lk + 3][lr + 64] = w1.w;
        __syncthreads();
#pragma unroll
        for (int k = 0; k < 16; ++k) {
            const float4 av0 = *(const float4*)&As[k][tx * 4];
            const float4 av1 = *(const float4*)&As[k][64 + tx * 4];
            const float4 bv0 = *(const float4*)&Ws[k][ty * 4];
            const float4 bv1 = *(const float4*)&Ws[k][64 + ty * 4];
            float a[8] = {av0.x, av0.y, av0.z, av0.w, av1.x, av1.y, av1.z, av1.w};
            float b[8] = {bv0.x, bv0.y, bv0.z, bv0.w, bv1.x, bv1.y, bv1.z, bv1.w};
#pragma unroll
            for (int i = 0; i < 8; ++i)
#pragma unroll
                for (int j = 0; j < 8; ++j) acc[i][j] = fmaf(a[i], b[j], acc[i][j]);
        }
    }

    const float4 bv0 = *(const float4*)&bias[n0 + ty * 4];
    const float4 bv1 = *(const float4*)&bias[n0 + 64 + ty * 4];
    const float bb[8] = {bv0.x, bv0.y, bv0.z, bv0.w, bv1.x, bv1.y, bv1.z, bv1.w};
#pragma unroll
    for (int i = 0; i < 8; ++i) {
        int m = m0 + ((i < 4) ? (tx * 4 + i) : (64 + tx * 4 + (i - 4)));
        float4 v0, v1;
        v0.x = acc[i][0] + bb[0]; v0.y = acc[i][1] + bb[1];
        v0.z = acc[i][2] + bb[2]; v0.w = acc[i][3] + bb[3];
        v1.x = acc[i][4] + bb[4]; v1.y = acc[i][5] + bb[5];
        v1.z = acc[i][6] + bb[6]; v1.w = acc[i][7] + bb[7];
        *(float4*)&C[(size_t)m * N + n0 + ty * 4] = v0;
        *(float4*)&C[(size_t)m * N + n0 + 64 + ty * 4] = v1;
    }
}

// ---------------------------------------------------------------------------
// state init: hT[j][b] = h0[b][j] (b<50 else 0), same for cT
// ---------------------------------------------------------------------------
__global__ void init_state(const float* __restrict__ h0, const float* __restrict__ c0,
                           float* __restrict__ hT, float* __restrict__ cT) {
    int idx = blockIdx.x * blockDim.x + threadIdx.x;
    if (idx >= H_ * BP) return;
    int j = idx >> 6, b = idx & 63;
    float hv = (b < B_) ? h0[b * H_ + j] : 0.0f;
    float cv = (b < B_) ? c0[b * H_ + j] : 0.0f;
    hT[idx] = hv;
    cT[idx] = cv;
}

// ---------------------------------------------------------------------------
// Persistent LSTM scan: one launch per layer. 256 blocks, each owns 2
// h-components (8 gate rows). W_hh slice staged to LDS ONCE, then 512 steps
// with a device-scope monotonic-counter grid barrier between steps.
// hT double-buffered (A=even-step input, B=odd-step input).
// ---------------------------------------------------------------------------
__global__ __launch_bounds__(256, 1) void lstm_scan(
    const float* __restrict__ xg,     // [B][T][NG], bias already included
    float* __restrict__ hTa,          // [H][BP] input at even t
    float* __restrict__ hTb,          // [H][BP] input at odd t
    float* __restrict__ cT,           // [H][BP]
    const float* __restrict__ W_hh,   // [NG][H]
    float* __restrict__ hs,           // [B][T][H] or nullptr
    int* __restrict__ bar) {
    __shared__ float w_lds[8][H_];    // 16 KB
    __shared__ float g_lds[8][BP];    // 2 KB
    const int tid = threadIdx.x;
    const int j0 = blockIdx.x * 2;

    // stage 8 W_hh rows -> LDS once (coalesced float4)
#pragma unroll
    for (int it = 0; it < 4; ++it) {
        int idx = tid + it * 256;          // float4 index, 0..1023
        int r = idx >> 7;                  // row 0..7 (128 float4 per row)
        int kk = (idx & 127) << 2;         // float offset in row
        int row = (r >> 1) * H_ + j0 + (r & 1);
        *(float4*)&w_lds[r][kk] = *(const float4*)&W_hh[(size_t)row * H_ + kk];
    }
    __syncthreads();

    const int bl = tid & 31;    // batch lane 0..31
    const int r  = tid >> 5;    // gate-row slot 0..7
    const int q  = r >> 1;
    const int row = q * 512 + j0 + (r & 1);
    const bool has1 = (bl + 32 < B_);
    const float* xg_p0 = xg + (size_t)bl * T_ * NG_ + row;
    const float* xg_p1 = xg + (size_t)(bl + 32) * T_ * NG_ + row;

    // preload xg for t=0
    float x0 = xg_p0[0];
    float x1 = has1 ? xg_p1[0] : 0.0f;

    const int jj2 = tid >> 6;   // writer decomposition (tid<128)
    const int wb  = tid & 63;
    const int wj  = j0 + jj2;

    for (int t = 0; t < T_; ++t) {
        const float* hin  = (t & 1) ? hTb : hTa;
        float*       hout = (t & 1) ? hTa : hTb;

        float acc0 = 0.0f, acc1 = 0.0f;
        const float* hp = hin + bl;
#pragma unroll 4
        for (int k = 0; k < H_; k += 4) {
            const float4 w4 = *(const float4*)&w_lds[r][k];
            acc0 = fmaf(w4.x, hp[(k + 0) * BP],      acc0);
            acc1 = fmaf(w4.x, hp[(k + 0) * BP + 32], acc1);
            acc0 = fmaf(w4.y, hp[(k + 1) * BP],      acc0);
            acc1 = fmaf(w4.y, hp[(k + 1) * BP + 32], acc1);
            acc0 = fmaf(w4.z, hp[(k + 2) * BP],      acc0);
            acc1 = fmaf(w4.z, hp[(k + 2) * BP + 32], acc1);
            acc0 = fmaf(w4.w, hp[(k + 3) * BP],      acc0);
            acc1 = fmaf(w4.w, hp[(k + 3) * BP + 32], acc1);
        }
        g_lds[r][bl]      = acc0 + x0;
        g_lds[r][bl + 32] = acc1 + x1;
        __syncthreads();

        if (tid < 128) {
            if (wb < B_) {
                float iv = g_lds[0 + jj2][wb];
                float fv = g_lds[2 + jj2][wb];
                float gv = g_lds[4 + jj2][wb];
                float ov = g_lds[6 + jj2][wb];
                float c_old = cT[wj * BP + wb];
                float cn = sigmf(fv) * c_old + sigmf(iv) * tanh_fast(gv);
                float hn = sigmf(ov) * tanh_fast(cn);
                cT[wj * BP + wb] = cn;
                hout[wj * BP + wb] = hn;
                if (hs) hs[((size_t)wb * T_ + t) * H_ + wj] = hn;
            } else {
                hout[wj * BP + wb] = 0.0f;   // keep pad lanes clean
            }
        }

        // cross-step prefetch of xg (read-only, no barrier dependency)
        if (t + 1 < T_) {
            x0 = xg_p0[(size_t)(t + 1) * NG_];
            x1 = has1 ? xg_p1[(size_t)(t + 1) * NG_] : 0.0f;
        }

        // grid barrier: all hout writes done (syncthreads orders block-local),
        // release-add publishes them agent-wide; acquire-load + syncthreads
        // makes other blocks' writes visible to every wave in this block.
        __syncthreads();
        if (tid == 0) {
            __hip_atomic_fetch_add(bar, 1, __ATOMIC_RELEASE, __HIP_MEMORY_SCOPE_AGENT);
            const int target = NBLK * (t + 1);
            while (__hip_atomic_load(bar, __ATOMIC_ACQUIRE, __HIP_MEMORY_SCOPE_AGENT) < target) {}
        }
        __syncthreads();
    }
}

// ---------------------------------------------------------------------------
// head
// ---------------------------------------------------------------------------
__global__ __launch_bounds__(512) void head(
    const float* __restrict__ hT, const float* __restrict__ lin1_W,
    const float* __restrict__ lin1_b, const float* __restrict__ lin2_W,
    const float* __restrict__ lin2_b, float* __restrict__ out) {
    __shared__ float zs[B_][10];
    int tid = threadIdx.x;
    if (tid < B_ * 10) {
        int b = tid / 10, u = tid % 10;
        float acc = lin1_b[u];
        for (int j = 0; j < H_; ++j)
            acc = fmaf(hT[j * BP + b], lin1_W[u * H_ + j], acc);
        zs[b][u] = tanh_fast(acc);
    }
    __syncthreads();
    if (tid < B_ * 2) {
        int b = tid >> 1, o = tid & 1;
        float acc = lin2_b[o];
#pragma unroll
        for (int u = 0; u < 10; ++u)
            acc = fmaf(zs[b][u], lin2_W[o * 10 + u], acc);
        out[b * 2 + o] = acc;
    }
}

// ---------------------------------------------------------------------------
extern "C" void kernel_launch(void* const* d_in, const int* in_sizes, int n_in,
                              void* d_out, int out_size, void* d_ws, size_t ws_size,
                              hipStream_t stream) {
    const float* input  = (const float*)d_in[0];
    const float* pca_W  = (const float*)d_in[1];
    const float* pca_b  = (const float*)d_in[2];
    const float* W_ih0  = (const float*)d_in[3];
    const float* W_hh0  = (const float*)d_in[4];
    const float* b0     = (const float*)d_in[5];
    const float* W_ih1  = (const float*)d_in[6];
    const float* W_hh1  = (const float*)d_in[7];
    const float* b1     = (const float*)d_in[8];
    const float* h0     = (const float*)d_in[9];
    const float* c0     = (const float*)d_in[10];
    const float* lin1_W = (const float*)d_in[11];
    const float* lin1_b = (const float*)d_in[12];
    const float* lin2_W = (const float*)d_in[13];
    const float* lin2_b = (const float*)d_in[14];
    float* out = (float*)d_out;

    float* ws = (float*)d_ws;
    size_t off = 0;
    float* xg   = ws + off; off += (size_t)B_ * T_ * NG_;  // 52.4M floats
    float* xbuf = ws + off; off += (size_t)B_ * T_ * H_;   // 13.1M floats
    float* hs0  = xbuf;                                    // alias: xbuf dead before hs0 born
    float* hT0  = ws + off; off += H_ * BP;
    float* hT1  = ws + off; off += H_ * BP;
    float* cT   = ws + off; off += H_ * BP;
    int*   bars = (int*)(ws + off); off += 64;             // bar0 @ +0, bar1 @ +32

    const int M = B_ * T_;  // 25600

    // zero barrier counters (ws is re-poisoned 0xAA before every timed launch)
    hipMemsetAsync(bars, 0, 64 * sizeof(float), stream);

    // 1. pca: xbuf = input @ pca_W^T + pca_b   (M x 512, K=1024)
    {
        dim3 g(H_ / 128, M / 128);
        gemm_bias<<<g, 256, 0, stream>>>(input, pca_W, pca_b, xbuf, M, H_, I_);
    }
    // 2. xg0 = xbuf @ W_ih0^T + b0             (M x 2048, K=512)
    {
        dim3 g(NG_ / 128, M / 128);
        gemm_bias<<<g, 256, 0, stream>>>(xbuf, W_ih0, b0, xg, M, NG_, H_);
    }
    // 3. layer-0 scan (persistent; writes hs0)
    init_state<<<(H_ * BP) / 256, 256, 0, stream>>>(h0, c0, hT0, cT);
    lstm_scan<<<NBLK, 256, 0, stream>>>(xg, hT0, hT1, cT, W_hh0, hs0, bars);
    // 4. xg1 = hs0 @ W_ih1^T + b1
    {
        dim3 g(NG_ / 128, M / 128);
        gemm_bias<<<g, 256, 0, stream>>>(hs0, W_ih1, b1, xg, M, NG_, H_);
    }
    // 5. layer-1 scan (no hs store; final h lands in hT0 since T even)
    init_state<<<(H_ * BP) / 256, 256, 0, stream>>>(h0 + B_ * H_, c0 + B_ * H_, hT0, cT);
    lstm_scan<<<NBLK, 256, 0, stream>>>(xg, hT0, hT1, cT, W_hh1, nullptr, bars + 32);
    // 6. head
    head<<<1, 512, 0, stream>>>(hT0, lin1_W, lin1_b, lin2_W, lin2_b, out);
}